// Round 1
// 261.296 us; speedup vs baseline: 1.1477x; 1.1477x over previous
//
#include <hip/hip_runtime.h>

// SymmetricContraction: out[b,c] = sum_w x_w U1[w] w1[b,c]
//                               + sum_{w,v}   x_w x_v   (U2 . w2[b,:,c])_{wv}
//                               + sum_{w,v,i} x_w x_v x_i (U3 . w3[b,:,c])_{wvi}
// U3 pre-symmetrized onto 816 multisets {a<=b<=c}: 94208 -> 18768 MACs/(b,c).
//
// This version: the U3 table is wave-uniform, so it is fetched via the SCALAR
// pipe (inline-asm s_load_dwordx16 -> SGPRs), not LDS broadcast reads. The old
// kernel was LDS-pipe-bound (16 waves x 816 x 6 ds_read_b128 broadcast ~ 540k
// cyc/CU = the whole 224us). FMAs consume the SGPR operand directly
// (v_fmac_f32 v, s, v). Two U-rows (48 floats = 3x s_load_dwordx16) per fetch
// amortize the in-asm lgkmcnt(0) wait; 4 waves/SIMD TLP hides SMEM latency.

#define B_   1024
#define C_   256
#define L_   16
#define E_   10
#define K3_  23
#define K2_  4

#define NM3  816   // #multisets a<=b<=c of 16
#define NM2  136   // #pairs a<=b
#define K3P  24    // k padded to 24 floats per row (96B)

typedef float f32x16 __attribute__((ext_vector_type(16)));

__device__ __host__ __forceinline__ int tri_(int n) { return n * (n + 1) / 2; }
__device__ __host__ __forceinline__ int tet_(int n) { return n * (n + 1) * (n + 2) / 6; }

// ---------------- prep: symmetrize U3 / U2 into workspace ----------------
// Closed-form multiset index (no per-thread scan): thread per (a,b,c) in L^3.
__global__ void prep_kernel(const float* __restrict__ U3,
                            const float* __restrict__ U2,
                            float* __restrict__ wsU3,
                            float* __restrict__ wsU2) {
  int tid = blockIdx.x * blockDim.x + threadIdx.x;
  if (tid < L_ * L_ * L_) {
    const int a = tid >> 8, b = (tid >> 4) & 15, c = tid & 15;
    if (a <= b && b <= c) {
      // rank of multiset (a<=b<=c) in lexicographic order
      const int m = (tet_(16) - tet_(16 - a)) + (tri_(16 - a) - tri_(16 - b)) + (c - b);
      int pw[6] = {a, a, b, b, c, c};
      int pv[6] = {b, c, a, c, a, b};
      int pi[6] = {c, b, c, a, b, a};
      bool use[6];
      for (int p = 0; p < 6; p++) {
        bool dup = false;
        for (int q = 0; q < p; q++)
          dup = dup || (pw[p] == pw[q] && pv[p] == pv[q] && pi[p] == pi[q]);
        use[p] = !dup;
      }
      for (int k = 0; k < K3_; k++) {
        float s = 0.f;
        for (int p = 0; p < 6; p++)
          if (use[p]) s += U3[((pw[p] * L_ + pv[p]) * L_ + pi[p]) * K3_ + k];
        wsU3[m * K3P + k] = s;
      }
      wsU3[m * K3P + K3_] = 0.f;  // pad
    }
  } else if (tid < L_ * L_ * L_ + L_ * L_) {
    const int p = tid - L_ * L_ * L_;
    const int a = p >> 4, b = p & 15;
    if (a <= b) {
      const int pidx = (136 - tri_(16 - a)) + (b - a);
      for (int k2 = 0; k2 < K2_; k2++) {
        float s = U2[(a * L_ + b) * K2_ + k2];
        if (a != b) s += U2[(b * L_ + a) * K2_ + k2];
        wsU2[pidx * K2_ + k2] = s;
      }
    }
  }
}

// ---------------- main: one thread per (b,c) ----------------
// block = 1024 threads = 4 b's x 256 c's; grid = 256 blocks (1 per CU).
__global__ __launch_bounds__(1024) void symcon_kernel(
    const float* __restrict__ x,   // [B,C,L]
    const float* __restrict__ y,   // [B,E]
    const float* __restrict__ U1,  // [L,1]
    const float* __restrict__ W3,  // [E,K3,C]
    const float* __restrict__ W2,  // [E,K2,C]
    const float* __restrict__ W1,  // [E,1,C]
    const float* __restrict__ wsU3,
    const float* __restrict__ wsU2,
    float* __restrict__ out)       // [B,C]
{
  __shared__ float sU2[NM2 * K2_];   // 2176 B
  __shared__ float sU1[L_];
  __shared__ float sY[4 * E_];
  __shared__ float sX[1024 * 17];    // 69632 B (stride 17: odd -> 2-way aliasing only)

  const int tid  = threadIdx.x;
  const int c    = tid & (C_ - 1);
  const int bsub = tid >> 8;
  const int row  = blockIdx.x * 1024 + tid;  // == b*C_ + c

  // stage small tables
  for (int i = tid; i < NM2 * K2_ / 4; i += 1024)
    ((float4*)sU2)[i] = ((const float4*)wsU2)[i];
  if (tid < L_) sU1[tid] = U1[tid];
  if (tid < 4 * E_) {
    int bb = blockIdx.x * 4 + tid / E_;
    sY[tid] = y[bb * E_ + tid % E_];
  }

  // stage this thread's x row (coalesced float4 global reads)
  float* xrow = &sX[tid * 17];
  {
    const float4* xg = (const float4*)(x + (size_t)row * L_);
    #pragma unroll
    for (int i = 0; i < 4; i++) {
      float4 v = xg[i];
      xrow[i * 4 + 0] = v.x; xrow[i * 4 + 1] = v.y;
      xrow[i * 4 + 2] = v.z; xrow[i * 4 + 3] = v.w;
    }
    xrow[16] = 0.f;  // pad slot: safe value if the tail path gets speculated
  }
  __syncthreads();

  // ---- nu=3 core: t[k] = sum_m x_a x_b x_c * Us3[m,k] ----
  // U rows fetched 2-at-a-time via scalar loads into SGPRs (zero LDS/VALU cost).
  float t[K3P];
  #pragma unroll
  for (int k = 0; k < K3P; k++) t[k] = 0.f;

  const float* up = wsU3;  // wave-uniform pointer -> SGPR pair
  for (int a = 0; a < L_; a++) {
    const float xa = xrow[a];
    for (int b = a; b < L_; b++) {
      const float xab = xa * xrow[b];
      for (int cc = b; cc < L_; cc += 2) {
        f32x16 u0, u1, u2;  // 48 floats = rows m, m+1
        asm volatile(
            "s_load_dwordx16 %0, %3, 0x0\n\t"
            "s_load_dwordx16 %1, %3, 0x40\n\t"
            "s_load_dwordx16 %2, %3, 0x80\n\t"
            "s_waitcnt lgkmcnt(0)"
            : "=s"(u0), "=s"(u1), "=s"(u2)
            : "s"(up));
        const bool pair = (cc + 1 < L_);
        const float p0 = xab * xrow[cc];
        const float p1 = pair ? xab * xrow[cc + 1] : 0.f;
        // row m: k0..15 in u0, k16..23 in u1[0..7]
        #pragma unroll
        for (int k = 0; k < 16; k++) t[k] += p0 * u0[k];
        #pragma unroll
        for (int k = 0; k < 8; k++)  t[16 + k] += p0 * u1[k];
        // row m+1: k0..7 in u1[8..15], k8..23 in u2  (p1==0 on odd tail;
        // the over-read past row 815 lands in wsU2 -> valid memory, times 0)
        #pragma unroll
        for (int k = 0; k < 8; k++)  t[k] += p1 * u1[8 + k];
        #pragma unroll
        for (int k = 0; k < 16; k++) t[8 + k] += p1 * u2[k];
        up += pair ? 2 * K3P : K3P;
      }
    }
  }

  // ---- epilogue ----
  float yreg[E_];
  {
    const float* yb = &sY[bsub * E_];
    #pragma unroll
    for (int e = 0; e < E_; e++) yreg[e] = yb[e];
  }

  float result = 0.f;
  // nu=3: contract t with w3[b,:,c]  (W3 reads coalesced over c)
  for (int k = 0; k < K3_; k++) {
    float w3k = 0.f;
    #pragma unroll
    for (int e = 0; e < E_; e++) w3k += W3[(e * K3_ + k) * C_ + c] * yreg[e];
    result += t[k] * w3k;
  }

  // nu=2
  float w2r[K2_];
  #pragma unroll
  for (int k2 = 0; k2 < K2_; k2++) {
    float s = 0.f;
    #pragma unroll
    for (int e = 0; e < E_; e++) s += W2[(e * K2_ + k2) * C_ + c] * yreg[e];
    w2r[k2] = s;
  }
  {
    float acc2 = 0.f;
    int p = 0;
    for (int a = 0; a < L_; a++) {
      const float xa = xrow[a];
      for (int b2 = a; b2 < L_; b2++) {
        const float pab = xa * xrow[b2];
        const float4 uv = *((const float4*)&sU2[p * K2_]);
        acc2 += pab * (uv.x * w2r[0] + uv.y * w2r[1] + uv.z * w2r[2] + uv.w * w2r[3]);
        p++;
      }
    }
    result += acc2;
  }

  // nu=1
  {
    float w1v = 0.f;
    #pragma unroll
    for (int e = 0; e < E_; e++) w1v += W1[e * C_ + c] * yreg[e];
    float u1x = 0.f;
    #pragma unroll
    for (int w = 0; w < L_; w++) u1x += sU1[w] * xrow[w];
    result += w1v * u1x;
  }

  out[row] = result;
}

extern "C" void kernel_launch(void* const* d_in, const int* in_sizes, int n_in,
                              void* d_out, int out_size, void* d_ws, size_t ws_size,
                              hipStream_t stream) {
  const float* x  = (const float*)d_in[0];
  const float* y  = (const float*)d_in[1];
  const float* U3 = (const float*)d_in[2];
  const float* U2 = (const float*)d_in[3];
  const float* U1 = (const float*)d_in[4];
  const float* W3 = (const float*)d_in[5];
  const float* W2 = (const float*)d_in[6];
  const float* W1 = (const float*)d_in[7];
  float* out = (float*)d_out;

  float* wsU3 = (float*)d_ws;                 // 816*24 floats = 78336 B
  float* wsU2 = wsU3 + NM3 * K3P;             // 136*4 floats  =  2176 B

  prep_kernel<<<dim3(17), dim3(256), 0, stream>>>(U3, U2, wsU3, wsU2);
  symcon_kernel<<<dim3(B_ * C_ / 1024), dim3(1024), 0, stream>>>(
      x, y, U1, W3, W2, W1, wsU3, wsU2, out);
}